// Round 5
// baseline (945.814 us; speedup 1.0000x reference)
//
#include <hip/hip_runtime.h>
#include <cstdint>
#include <cstddef>

// GCN_52012053955018 — round 5
//
// Changes vs round 4:
//  * scatter_pad (243us, WRITE_SIZE 198MB = 1 dirty line/edge) replaced by a
//    deterministic radix partition into 256-row bins:
//      part_hist (LDS hist, no per-edge global atomics) -> scanA (per-bin
//      prefix over blocks) -> scanB (bin bases) -> part_scatter (LDS cursors,
//      writes to consecutive addresses per (block,bin) run).
//  * spmm: block-per-bin, LDS accumulator (pitch 9 to spread banks),
//    atomic-free in global memory; mid fused into spmm1 epilogue, final
//    (acc@W2+b2 -> log_softmax) fused into spmm2 epilogue.
//  * dense: wave-k-split — wave w handles k-quarter for all 64 nodes, all 8 j
//    (24 accums); weights wave-uniform -> s_load; each x float read from LDS
//    once (b128), cross-wave reduce in reused LDS.
//
// ws layout (floats):
//   [xw1 8n][right 8n][h 8n][acc1 8n][acc2 8n][W1T 4096][VT 4096][VSQT 4096]
//   [ints: binBase 520 | binTotal 512 | blockHist 1024*nbin][binned e*uint2]

#define NFEAT 512
#define NHID 8
#define NCLASS 16
#define NB_PART 1024
#define NBIN_MAX 512

// ---------------- prep: weight transposes (+V^2) + optional zero ----------------
__global__ __launch_bounds__(256) void prep_kernel(
    const float* __restrict__ W1, const float* __restrict__ V,
    float* __restrict__ W1T, float* __restrict__ VT, float* __restrict__ VSQT,
    uint4* __restrict__ zero_base, int zero_count16)
{
    int tid = blockIdx.x * 256 + threadIdx.x;
    if (tid < NFEAT * NHID) {
        int k = tid >> 3, j = tid & 7;
        W1T[j * NFEAT + k] = W1[tid];
        float vv = V[tid];
        VT[j * NFEAT + k] = vv;
        VSQT[j * NFEAT + k] = vv * vv;
    }
    int stride = gridDim.x * 256;
    for (int i = tid; i < zero_count16; i += stride)
        zero_base[i] = make_uint4(0u, 0u, 0u, 0u);
}

// ---------------- dense: wave-k-split ----------------
// Block = 64 nodes, 4 waves. Wave w handles k in {ch*128 + w*32 .. +31} for
// ch=0..3, for ALL 64 nodes (lane = node) and ALL 8 j. Weights wave-uniform.
#define DB_NODES 64
#define XS_PITCH 132   // floats; 528B row pitch (16B aligned)
__global__ __launch_bounds__(256) void dense_kernel(
    const float* __restrict__ x,
    const float* __restrict__ W1T, const float* __restrict__ VT,
    const float* __restrict__ VSQT,
    const float* __restrict__ gamma, const float* __restrict__ beta,
    float* __restrict__ xw1, float* __restrict__ right, int n_nodes)
{
    __shared__ float xs[DB_NODES * XS_PITCH];  // 33792 B; reused for reduction
    const int tid = threadIdx.x;
    const int lane = tid & 63;
    const int w = __builtin_amdgcn_readfirstlane(tid >> 6);  // 0..3, uniform
    const int w32 = w * 32;
    const int node0 = blockIdx.x * DB_NODES;

    float a1[8], av[8], a2[8];
#pragma unroll
    for (int j = 0; j < 8; ++j) { a1[j] = 0.f; av[j] = 0.f; a2[j] = 0.f; }

    for (int ch = 0; ch < 4; ++ch) {
        __syncthreads();
        // stage 64 rows x 128 floats = 2048 float4 slots / 256 threads
#pragma unroll
        for (int t = 0; t < 8; ++t) {
            int i = tid + t * 256;
            int row = i >> 5, col = i & 31;
            int gr = node0 + row;
            if (gr >= n_nodes) gr = n_nodes - 1;
            float4 v = *(const float4*)(x + (size_t)gr * NFEAT + ch * 128 + col * 4);
            *(float4*)(xs + row * XS_PITCH + col * 4) = v;
        }
        __syncthreads();
        const int kg0 = ch * 128 + w32;
#pragma unroll
        for (int kk = 0; kk < 8; ++kk) {
            float4 xv = *(const float4*)(xs + lane * XS_PITCH + w32 + kk * 4);
            float qx = xv.x * xv.x, qy = xv.y * xv.y, qz = xv.z * xv.z, qw = xv.w * xv.w;
            const int kg = kg0 + kk * 4;
#pragma unroll
            for (int j = 0; j < 8; ++j) {
                const float* wp = W1T + j * NFEAT + kg;   // wave-uniform -> s_load
                const float* vp = VT + j * NFEAT + kg;
                const float* sp = VSQT + j * NFEAT + kg;
                a1[j] += xv.x * wp[0] + xv.y * wp[1] + xv.z * wp[2] + xv.w * wp[3];
                av[j] += xv.x * vp[0] + xv.y * vp[1] + xv.z * vp[2] + xv.w * vp[3];
                a2[j] += qx * sp[0] + qy * sp[1] + qz * sp[2] + qw * sp[3];
            }
        }
    }

    // cross-wave reduce via LDS (reuse xs: 6144 floats <= 8448)
    __syncthreads();
    float* red = xs;
#pragma unroll
    for (int j = 0; j < 8; ++j) {
        red[((0 * 8 + j) * 4 + w) * 64 + lane] = a1[j];
        red[((1 * 8 + j) * 4 + w) * 64 + lane] = av[j];
        red[((2 * 8 + j) * 4 + w) * 64 + lane] = a2[j];
    }
    __syncthreads();
    int node = node0 + lane;
    if (node < n_nodes) {
#pragma unroll
        for (int u = 0; u < 2; ++u) {
            int jj = w + u * 4;   // wave-uniform
            float s1 = 0.f, sv = 0.f, s2 = 0.f;
#pragma unroll
            for (int q = 0; q < 4; ++q) {
                s1 += red[((0 * 8 + jj) * 4 + q) * 64 + lane];
                sv += red[((1 * 8 + jj) * 4 + q) * 64 + lane];
                s2 += red[((2 * 8 + jj) * 4 + q) * 64 + lane];
            }
            xw1[node * 8 + jj] = s1;
            float rr = fmaxf(0.5f * (sv * sv - s2), 0.f);
            right[node * 8 + jj] = 0.5f * (gamma[jj] * rr + beta[jj]);
        }
    }
}

// ---------------- partition pass 1: per-block histogram ----------------
__global__ __launch_bounds__(256) void part_hist_kernel(
    const int* __restrict__ rows, int* __restrict__ blockHist,
    int nbin, int chunk, int e)
{
    __shared__ int lh[NBIN_MAX];
    int b = blockIdx.x, t = threadIdx.x;
    for (int i = t; i < nbin; i += 256) lh[i] = 0;
    __syncthreads();
    int s = b * chunk;
    int end = s + chunk; if (end > e) end = e;
    for (int i = s + t; i < end; i += 256)
        atomicAdd(&lh[rows[i] >> 8], 1);
    __syncthreads();
    for (int i = t; i < nbin; i += 256)
        blockHist[(size_t)b * nbin + i] = lh[i];
}

// ---------------- pass 2a: per-bin exclusive prefix over the 1024 blocks ----------------
__global__ __launch_bounds__(256) void scanA_kernel(
    int* __restrict__ blockHist, int* __restrict__ binTotal, int nbin)
{
    __shared__ int s[256];
    int bin = blockIdx.x, t = threadIdx.x;
    int v[4];
    int sum = 0;
#pragma unroll
    for (int u = 0; u < 4; ++u) {
        int bb = t * 4 + u;                       // NB_PART == 1024 == 256*4
        int d = blockHist[(size_t)bb * nbin + bin];
        v[u] = sum;
        sum += d;
    }
    s[t] = sum;
    __syncthreads();
    for (int off = 1; off < 256; off <<= 1) {
        int add = (t >= off) ? s[t - off] : 0;
        __syncthreads();
        s[t] += add;
        __syncthreads();
    }
    int toff = (t > 0) ? s[t - 1] : 0;
#pragma unroll
    for (int u = 0; u < 4; ++u) {
        int bb = t * 4 + u;
        blockHist[(size_t)bb * nbin + bin] = toff + v[u];
    }
    if (t == 255) binTotal[bin] = s[255];
}

// ---------------- pass 2b: bin bases ----------------
__global__ __launch_bounds__(512) void scanB_kernel(
    const int* __restrict__ binTotal, int* __restrict__ binBase, int nbin, int e)
{
    __shared__ int s[512];
    int t = threadIdx.x;
    int vv = (t < nbin) ? binTotal[t] : 0;
    s[t] = vv;
    __syncthreads();
    for (int off = 1; off < 512; off <<= 1) {
        int add = (t >= off) ? s[t - off] : 0;
        __syncthreads();
        s[t] += add;
        __syncthreads();
    }
    if (t < nbin) binBase[t] = s[t] - vv;   // exclusive
    if (t == 0) binBase[nbin] = e;
}

// ---------------- pass 3: clustered scatter ----------------
__global__ __launch_bounds__(256) void part_scatter_kernel(
    const int* __restrict__ rows, const int* __restrict__ cols,
    const float* __restrict__ vals, const int* __restrict__ blockHist,
    const int* __restrict__ binBase, uint2* __restrict__ binned,
    int nbin, int chunk, int e)
{
    __shared__ int cur[NBIN_MAX];
    int b = blockIdx.x, t = threadIdx.x;
    for (int i = t; i < nbin; i += 256)
        cur[i] = binBase[i] + blockHist[(size_t)b * nbin + i];
    __syncthreads();
    int s = b * chunk;
    int end = s + chunk; if (end > e) end = e;
    for (int i = s + t; i < end; i += 256) {
        int r = rows[i];
        int pos = atomicAdd(&cur[r >> 8], 1);
        binned[pos] = make_uint2(((uint32_t)(r & 255) << 17) | (uint32_t)cols[i],
                                 __float_as_uint(vals[i]));
    }
}

// ---------------- spmm over bins, LDS accumulate ----------------
// mode 0: out = h = 0.5*relu(acc+b1) + right          (per-row 8 floats)
// mode 1: out = log_softmax(acc@W2 + b2)              (per-row 16 floats)
#define ACC_PITCH 9   // (9*rl + j) % 32 spreads banks (9 coprime 32)
__global__ __launch_bounds__(512) void spmm_bin_kernel(
    const int* __restrict__ binBase, const uint2* __restrict__ binned,
    const float* __restrict__ src, float* __restrict__ out,
    const float* __restrict__ right, const float* __restrict__ b1v,
    const float* __restrict__ W2, const float* __restrict__ b2,
    int mode, int n)
{
    __shared__ float acc[256 * ACC_PITCH];
    const int tid = threadIdx.x;
    const int bin = blockIdx.x;
    const int r0 = bin << 8;
    int nr = n - r0; if (nr > 256) nr = 256;

    for (int i = tid; i < 256 * ACC_PITCH; i += 512) acc[i] = 0.f;
    __syncthreads();

    int s0 = binBase[bin], s1 = binBase[bin + 1];
    for (int i = s0 + tid; i < s1; i += 512) {
        uint2 ev = binned[i];
        float v = __uint_as_float(ev.y);
        int rl = (int)(ev.x >> 17);
        int c  = (int)(ev.x & 0x1FFFF);
        const float4* sp = (const float4*)(src + (size_t)c * 8);
        float4 lo = sp[0], hi = sp[1];
        float* a = acc + rl * ACC_PITCH;
        atomicAdd(a + 0, v * lo.x);
        atomicAdd(a + 1, v * lo.y);
        atomicAdd(a + 2, v * lo.z);
        atomicAdd(a + 3, v * lo.w);
        atomicAdd(a + 4, v * hi.x);
        atomicAdd(a + 5, v * hi.y);
        atomicAdd(a + 6, v * hi.z);
        atomicAdd(a + 7, v * hi.w);
    }
    __syncthreads();

    if (mode == 0) {
        // one thread per row
        if (tid < nr) {
            const float* a = acc + tid * ACC_PITCH;
            const float* rr = right + (size_t)(r0 + tid) * 8;
            float o[8];
#pragma unroll
            for (int j = 0; j < 8; ++j)
                o[j] = 0.5f * fmaxf(a[j] + b1v[j], 0.f) + rr[j];
            float4* op = (float4*)(out + (size_t)(r0 + tid) * 8);
            op[0] = make_float4(o[0], o[1], o[2], o[3]);
            op[1] = make_float4(o[4], o[5], o[6], o[7]);
        }
    } else {
        // two threads per row: halves of the 16 classes; pair-reduce via shfl
        int row = tid >> 1, half = tid & 1;
        if (row < nr) {
            float hv[8];
            const float* a = acc + row * ACC_PITCH;
#pragma unroll
            for (int j = 0; j < 8; ++j) hv[j] = a[j];
            float z[8];
#pragma unroll
            for (int c8 = 0; c8 < 8; ++c8) {
                int c = half * 8 + c8;
                float s = b2[c];
#pragma unroll
                for (int j = 0; j < 8; ++j) s += hv[j] * W2[j * NCLASS + c];
                z[c8] = s;
            }
            float m = z[0];
#pragma unroll
            for (int c8 = 1; c8 < 8; ++c8) m = fmaxf(m, z[c8]);
            m = fmaxf(m, __shfl_xor(m, 1));
            float se = 0.f;
#pragma unroll
            for (int c8 = 0; c8 < 8; ++c8) se += __expf(z[c8] - m);
            se += __shfl_xor(se, 1);
            float l = m + __logf(se);
            float4* op = (float4*)(out + (size_t)(r0 + row) * 16 + half * 8);
            op[0] = make_float4(z[0] - l, z[1] - l, z[2] - l, z[3] - l);
            op[1] = make_float4(z[4] - l, z[5] - l, z[6] - l, z[7] - l);
        }
    }
}

// ---------------- fallback path (round-4): atomic spmm + mid + final ----------------
__global__ __launch_bounds__(256) void spmm8_kernel(
    const int* __restrict__ rows, const int* __restrict__ cols,
    const float* __restrict__ vals, const float* __restrict__ src,
    float* __restrict__ acc, int n_edges)
{
    int tid = blockIdx.x * 256 + threadIdx.x;
    int e = tid >> 1;
    if (e >= n_edges) return;
    int hh = tid & 1;
    int r = rows[e], c = cols[e];
    float v = vals[e];
    float4 f = ((const float4*)src)[c * 2 + hh];
    float* d = acc + (size_t)r * NHID + hh * 4;
    unsafeAtomicAdd(d + 0, v * f.x);
    unsafeAtomicAdd(d + 1, v * f.y);
    unsafeAtomicAdd(d + 2, v * f.z);
    unsafeAtomicAdd(d + 3, v * f.w);
}

__global__ __launch_bounds__(256) void mid_kernel(
    const float* __restrict__ acc1, const float* __restrict__ right,
    const float* __restrict__ b1, float* __restrict__ h, int n4)
{
    int i = blockIdx.x * 256 + threadIdx.x;
    if (i >= n4) return;
    float4 a = ((const float4*)acc1)[i];
    float4 r = ((const float4*)right)[i];
    float4 b = ((const float4*)b1)[i & 1];
    float4 o;
    o.x = 0.5f * fmaxf(a.x + b.x, 0.f) + r.x;
    o.y = 0.5f * fmaxf(a.y + b.y, 0.f) + r.y;
    o.z = 0.5f * fmaxf(a.z + b.z, 0.f) + r.z;
    o.w = 0.5f * fmaxf(a.w + b.w, 0.f) + r.w;
    ((float4*)h)[i] = o;
}

__global__ __launch_bounds__(256) void final_kernel(
    const float* __restrict__ acc2, const float* __restrict__ W2,
    const float* __restrict__ b2, float* __restrict__ out, int n_nodes)
{
    int node = blockIdx.x * 256 + threadIdx.x;
    if (node >= n_nodes) return;
    float4 h0 = ((const float4*)acc2)[(size_t)node * 2];
    float4 h1 = ((const float4*)acc2)[(size_t)node * 2 + 1];
    float hv[NHID] = {h0.x, h0.y, h0.z, h0.w, h1.x, h1.y, h1.z, h1.w};
    float z[NCLASS];
#pragma unroll
    for (int c = 0; c < NCLASS; ++c) z[c] = b2[c];
#pragma unroll
    for (int j = 0; j < NHID; ++j)
#pragma unroll
        for (int c = 0; c < NCLASS; ++c) z[c] += hv[j] * W2[j * NCLASS + c];
    float m = z[0];
#pragma unroll
    for (int c = 1; c < NCLASS; ++c) m = fmaxf(m, z[c]);
    float s = 0.f;
#pragma unroll
    for (int c = 0; c < NCLASS; ++c) s += __expf(z[c] - m);
    float l = m + __logf(s);
    float4* o = (float4*)(out + (size_t)node * NCLASS);
#pragma unroll
    for (int q = 0; q < 4; ++q)
        o[q] = make_float4(z[4 * q + 0] - l, z[4 * q + 1] - l,
                           z[4 * q + 2] - l, z[4 * q + 3] - l);
}

extern "C" void kernel_launch(void* const* d_in, const int* in_sizes, int n_in,
                              void* d_out, int out_size, void* d_ws, size_t ws_size,
                              hipStream_t stream)
{
    const float* x     = (const float*)d_in[0];
    const int*   rows  = (const int*)  d_in[1];
    const int*   cols  = (const int*)  d_in[2];
    const float* vals  = (const float*)d_in[3];
    const float* W1    = (const float*)d_in[4];
    const float* b1    = (const float*)d_in[5];
    const float* W2    = (const float*)d_in[6];
    const float* b2    = (const float*)d_in[7];
    const float* V     = (const float*)d_in[8];
    const float* gamma = (const float*)d_in[9];
    const float* beta  = (const float*)d_in[10];

    const int n = in_sizes[0] / NFEAT;   // 100000
    const int e = in_sizes[1];           // 3200000
    const int nbin = (n + 255) >> 8;     // 391

    float* ws    = (float*)d_ws;
    float* xw1   = ws;                    // n*8
    float* right = ws + (size_t)n * 8;    // n*8
    float* h     = ws + (size_t)n * 16;   // n*8
    float* acc1  = ws + (size_t)n * 24;   // n*8 (fallback only)
    float* acc2  = ws + (size_t)n * 32;   // n*8 (fallback only)
    float* W1T   = ws + (size_t)n * 40;   // 4096
    float* VT    = W1T + NFEAT * NHID;    // 4096
    float* VSQT  = VT + NFEAT * NHID;     // 4096

    int* ibase     = (int*)(VSQT + NFEAT * NHID);
    int* binBase   = ibase;               // nbin+1 (alloc 520)
    int* binTotal  = ibase + 520;         // 512
    int* blockHist = ibase + 1032;        // NB_PART * nbin

    size_t ints_end = (size_t)n * 40 + 3 * NFEAT * NHID + 1032 + (size_t)NB_PART * nbin;
    size_t binned_off = (ints_end + 1) & ~(size_t)1;
    uint2* binned = (uint2*)(ws + binned_off);
    size_t needed = (binned_off + (size_t)e * 2) * 4;

    const bool use_bin = (ws_size >= needed) && (nbin <= NBIN_MAX);
    const int chunk = (e + NB_PART - 1) / NB_PART;
    const int dense_blocks = (n + DB_NODES - 1) / DB_NODES;

    if (use_bin) {
        prep_kernel<<<(NFEAT * NHID + 255) / 256, 256, 0, stream>>>(
            W1, V, W1T, VT, VSQT, (uint4*)ws, 0);

        part_hist_kernel<<<NB_PART, 256, 0, stream>>>(rows, blockHist, nbin, chunk, e);
        scanA_kernel<<<nbin, 256, 0, stream>>>(blockHist, binTotal, nbin);
        scanB_kernel<<<1, 512, 0, stream>>>(binTotal, binBase, nbin, e);
        part_scatter_kernel<<<NB_PART, 256, 0, stream>>>(
            rows, cols, vals, blockHist, binBase, binned, nbin, chunk, e);

        dense_kernel<<<dense_blocks, 256, 0, stream>>>(
            x, W1T, VT, VSQT, gamma, beta, xw1, right, n);

        // spmm1 + fused mid -> h
        spmm_bin_kernel<<<nbin, 512, 0, stream>>>(
            binBase, binned, xw1, h, right, b1, nullptr, nullptr, 0, n);
        // spmm2 + fused W2/log_softmax -> out
        spmm_bin_kernel<<<nbin, 512, 0, stream>>>(
            binBase, binned, h, (float*)d_out, nullptr, nullptr, W2, b2, 1, n);
    } else {
        // fallback: atomic spmm path; zero acc1+acc2 (n*16 floats = n*4 uint4)
        prep_kernel<<<(n * 4 + 255) / 256, 256, 0, stream>>>(
            W1, V, W1T, VT, VSQT, (uint4*)acc1, n * 4);

        dense_kernel<<<dense_blocks, 256, 0, stream>>>(
            x, W1T, VT, VSQT, gamma, beta, xw1, right, n);

        spmm8_kernel<<<(e * 2 + 255) / 256, 256, 0, stream>>>(rows, cols, vals, xw1, acc1, e);
        mid_kernel<<<(n * 2 + 255) / 256, 256, 0, stream>>>(acc1, right, b1, h, n * 2);
        spmm8_kernel<<<(e * 2 + 255) / 256, 256, 0, stream>>>(rows, cols, vals, h, acc2, e);
        final_kernel<<<(n + 255) / 256, 256, 0, stream>>>(acc2, W2, b2, (float*)d_out, n);
    }
}